// Round 5
// baseline (344.101 us; speedup 1.0000x reference)
//
#include <hip/hip_runtime.h>
#include <hip/hip_bf16.h>
#include <stdint.h>

// TernaryConv2d: y = conv2d(x, alpha*ternary(W), SAME) + b
// x: (32,56,56,256) NHWC fp32, W: (3,3,256,256) HWIO fp32, b: (256,) fp32
// Implicit GEMM: M=100352, N=256, K=2304. bf16 MFMA, alpha fp32 epilogue.
//
// R1: reduction atomics fixed (670->349).
// R2: XOR-swizzled LDS, kc-outer/tap-inner K-loop, fused sumabs (349->299).
// R3: 256x256/8-phase REGRESSED (grid-packing tail). REVERTED.
// R4/R5: atomics/memset removed (294). Fixed ~108us harness residue identified.
// R6: xpad eliminated, A reg-staged from fp32 x. conv 124->225: staging was
//     SERIAL (load->wait->convert->write->barrier), HBM latency exposed 36x.
//     FETCH 110->317MB but only 24% HBM => latency-bound, not BW-bound.
// R7: pipelined fused staging (T14 issue-early/write-late), double-buffered
//     LDS, ONE __syncthreads per K-step. Loads for tile ks+1 are issued at
//     the top of tile ks's compute section and consumed (convert+ds_write)
//     after the next barrier -> latency hidden under 32 MFMAs. The barrier's
//     vmcnt(0) drain only catches B-async ops issued a full MFMA phase ago.
//     Race-free with a single barrier (staging(ks) writes buf p, compute(ks-1)
//     reads buf p^1; no wave can lag 2 phases behind a barrier).
//     Numerically bitwise-identical to R5/R6.
//
// ws layout:
//   [0..2303]   : pr[288] double  — per-block sum|W| partials
//   [2560..4863]: qv[288] double  — per-block sum|W beyond t| partials
//   [5120..7423]: qc[288] ull     — per-block count-beyond partials
//   [8192..]    : WqT bf16 [256 co][2304 k]  (k = tap*256 + ci), 1.18MB

typedef __attribute__((ext_vector_type(8))) short short8;
typedef __attribute__((ext_vector_type(4))) float floatx4;

#define NW_ELEMS 589824        // 3*3*256*256
#define K_TOTAL 2304
#define PR_OFF 0
#define QV_OFF 2560
#define QC_OFF 5120
#define WQT_OFF 8192
#define RED_BLOCKS 288         // 288*256*8 == NW_ELEMS exactly

__device__ __forceinline__ void async16(const void* g, void* l) {
  __builtin_amdgcn_global_load_lds(
      (const __attribute__((address_space(1))) void*)g,
      (__attribute__((address_space(3))) void*)l, 16, 0, 0);
}

__device__ __forceinline__ ushort f2bf(float f) {
  __hip_bfloat16 h = __float2bfloat16(f);
  return *reinterpret_cast<ushort*>(&h);
}

// ---- sum|W| -> pr[bid] (288 blocks) ----
__global__ __launch_bounds__(256) void sumabs_kernel(
    const float* __restrict__ W, double* __restrict__ pr) {
  __shared__ double sds[4];
  double v = 0.0;
#pragma unroll
  for (int j = 0; j < 8; j++) {
    uint i = (blockIdx.x * 8 + j) * 256 + threadIdx.x;
    v += (double)fabsf(W[i]);
  }
#pragma unroll
  for (int off = 32; off; off >>= 1) v += __shfl_down(v, off);
  if ((threadIdx.x & 63) == 0) sds[threadIdx.x >> 6] = v;
  __syncthreads();
  if (threadIdx.x == 0) pr[blockIdx.x] = sds[0] + sds[1] + sds[2] + sds[3];
}

// ---- ternarize: WqT[co][k] in {-1,0,+1}; per-block alpha-stat partials ----
__global__ __launch_bounds__(256) void quant_kernel(
    const float* __restrict__ W, ushort* __restrict__ WqT,
    const double* __restrict__ pr, double* __restrict__ qv,
    unsigned long long* __restrict__ qc) {
  __shared__ double sds[4];
  __shared__ unsigned long long cds[4];
  double p = pr[threadIdx.x];
  if (threadIdx.x < 32) p += pr[256 + threadIdx.x];
#pragma unroll
  for (int off = 32; off; off >>= 1) p += __shfl_down(p, off);
  if ((threadIdx.x & 63) == 0) sds[threadIdx.x >> 6] = p;
  __syncthreads();
  double s = sds[0] + sds[1] + sds[2] + sds[3];
  float t = (float)(0.7 * (s / (double)NW_ELEMS));
  __syncthreads();  // sds reused below

  double v = 0.0;
  unsigned long long cnt = 0;
  ushort u[8];
#pragma unroll
  for (int j = 0; j < 8; j++) {
    uint i = (blockIdx.x * 8 + j) * 256 + threadIdx.x;
    float w = W[i];
    bool pos = (w > t), neg = (w < -t);
    u[j] = pos ? (ushort)0x3F80 : (neg ? (ushort)0xBF80 : (ushort)0);
    if (pos || neg) { v += (double)fabsf(w); cnt++; }
  }
  *(uint4*)(WqT + (size_t)threadIdx.x * K_TOTAL + blockIdx.x * 8) = *(uint4*)u;
#pragma unroll
  for (int off = 32; off; off >>= 1) {
    v += __shfl_down(v, off);
    cnt += __shfl_down(cnt, off);
  }
  if ((threadIdx.x & 63) == 0) { sds[threadIdx.x >> 6] = v; cds[threadIdx.x >> 6] = cnt; }
  __syncthreads();
  if (threadIdx.x == 0) {
    qv[blockIdx.x] = sds[0] + sds[1] + sds[2] + sds[3];
    qc[blockIdx.x] = cds[0] + cds[1] + cds[2] + cds[3];
  }
}

// ---- implicit-GEMM conv: 128x128 tile, BK=64, pipelined fused pad ----
// Per K-step ks (ONE barrier):
//   staging: convert pf-regs(ks) -> bf16, ds_write -> Alds[p]
//   __syncthreads()   // drains B-async(ks) [issued a phase ago] + A-writes
//   if ks<35: issue A-loads(ks+1)->regs, B-async(ks+1)->Blds[p^1]  (fly
//             under the MFMAs below; compiler inserts the counted waits)
//   compute: ds_read Alds[p]/Blds[p] (XOR-swizzled slots), 32 MFMA
__global__ __launch_bounds__(256, 2) void conv_kernel(
    const float* __restrict__ x, const ushort* __restrict__ WqT,
    const double* __restrict__ qv, const unsigned long long* __restrict__ qc,
    const float* __restrict__ bias, float* __restrict__ out) {
  __shared__ __attribute__((aligned(16))) ushort Alds[2][128 * 64];  // 32 KB
  __shared__ __attribute__((aligned(16))) ushort Blds[2][128 * 64];  // 32 KB
  __shared__ double ads[4];
  __shared__ double acs[4];
  uint tid = threadIdx.x;
  uint bm = blockIdx.x >> 1, bn = blockIdx.x & 1;

  // staging map: thread (rbase,chunk) handles global chunk ceff = chunk^(r&7)
  uint chunk = tid & 7;
  uint rbase = tid >> 3;       // 0..31
  uint ceff = chunk ^ (rbase & 7);
  int hh[4], ww[4];
  int abase[4];                // element offset of (n, h-1, w-1) + ceff*8
  const ushort* bsrc[4];
#pragma unroll
  for (int i = 0; i < 4; i++) {
    uint row = i * 32 + rbase;
    uint gm = bm * 128 + row;
    uint n = gm / 3136;
    uint rem = gm - n * 3136;
    uint h = rem / 56;
    uint w = rem - h * 56;
    hh[i] = (int)h;
    ww[i] = (int)w;
    abase[i] = (((int)n * 56 + (int)h - 1) * 56 + (int)w - 1) * 256 + (int)(ceff * 8);
    bsrc[i] = WqT + ((size_t)(bn * 128 + row) * K_TOTAL + ceff * 8);
  }

  floatx4 acc[4][4];
#pragma unroll
  for (int mt = 0; mt < 4; mt++)
#pragma unroll
    for (int nt = 0; nt < 4; nt++) acc[mt][nt] = (floatx4){0.f, 0.f, 0.f, 0.f};

  uint lane = tid & 63;
  uint wv = tid >> 6;
  uint wm = wv >> 1, wn = wv & 1;   // 2x2 wave grid, each 64x64
  uint fr = lane & 15, fq = lane >> 4;
  uint a_row = (wm * 64 + fr) * 128;  // + mt*2048 + swz-chunk*16 (bytes)
  uint b_row = (wn * 64 + fr) * 128;
  uint swz = (fr & 7) * 16;           // XOR byte offset applied to chunk slot

  // ---- prologue: issue tile 0 (A->regs, B->Blds[0]) ----
  float4 pf0[4], pf1[4];
  {
    // ks=0: kcq=0, tap=0 -> ky=0, kx=0
#pragma unroll
    for (int i = 0; i < 4; i++) {
      int ih = hh[i] - 1, iw = ww[i] - 1;
      bool valid = ((uint)ih < 56u) && ((uint)iw < 56u);
      pf0[i] = (float4){0.f, 0.f, 0.f, 0.f};
      pf1[i] = (float4){0.f, 0.f, 0.f, 0.f};
      if (valid) {
        const float* p = x + abase[i];
        pf0[i] = *(const float4*)p;
        pf1[i] = *(const float4*)(p + 4);
      }
    }
#pragma unroll
    for (int i = 0; i < 4; i++)
      async16(bsrc[i], (char*)&Blds[0][0] + i * 4096 + tid * 16);
  }

#pragma unroll 1
  for (int ks = 0; ks < 36; ks++) {
    uint p = (uint)ks & 1;
    char* Ab = (char*)&Alds[p][0];
    char* Bb = (char*)&Blds[p][0];

    // ---- staging: convert prefetched regs -> bf16 -> LDS ----
#pragma unroll
    for (int i = 0; i < 4; i++) {
      ushort u[8];
      u[0] = f2bf(pf0[i].x); u[1] = f2bf(pf0[i].y);
      u[2] = f2bf(pf0[i].z); u[3] = f2bf(pf0[i].w);
      u[4] = f2bf(pf1[i].x); u[5] = f2bf(pf1[i].y);
      u[6] = f2bf(pf1[i].z); u[7] = f2bf(pf1[i].w);
      *(uint4*)(Ab + i * 4096 + tid * 16) = *(uint4*)u;
    }
    __syncthreads();  // A-writes visible; B-async(ks) drained (vmcnt0)

    // ---- prefetch tile ks+1 (flies under the MFMAs below) ----
    if (ks < 35) {
      uint ks1 = (uint)ks + 1;
      uint kcq = ks1 / 9;
      uint tap = ks1 - kcq * 9;
      int ky = (int)(tap / 3);
      int kx = (int)(tap - ky * 3);
      int aoffe = (ky * 56 + kx) * 256 + (int)(kcq * 64);
      uint boffe = tap * 256 + kcq * 64;
#pragma unroll
      for (int i = 0; i < 4; i++) {
        int ih = hh[i] + ky - 1;
        int iw = ww[i] + kx - 1;
        bool valid = ((uint)ih < 56u) && ((uint)iw < 56u);
        pf0[i] = (float4){0.f, 0.f, 0.f, 0.f};
        pf1[i] = (float4){0.f, 0.f, 0.f, 0.f};
        if (valid) {
          const float* gp = x + (abase[i] + aoffe);
          pf0[i] = *(const float4*)gp;
          pf1[i] = *(const float4*)(gp + 4);
        }
      }
#pragma unroll
      for (int i = 0; i < 4; i++)
        async16(bsrc[i] + boffe, (char*)&Blds[p ^ 1][0] + i * 4096 + tid * 16);
    }

    // ---- compute on buffers p ----
#pragma unroll
    for (int kk = 0; kk < 2; kk++) {
      uint csl = ((uint)(kk * 64) + fq * 16) ^ swz;  // swizzled chunk slot
      short8 af[4], bfr[4];
#pragma unroll
      for (int mt = 0; mt < 4; mt++)
        af[mt] = *(const short8*)(Ab + a_row + mt * 2048 + csl);
#pragma unroll
      for (int nt = 0; nt < 4; nt++)
        bfr[nt] = *(const short8*)(Bb + b_row + nt * 2048 + csl);
#pragma unroll
      for (int mt = 0; mt < 4; mt++)
#pragma unroll
        for (int nt = 0; nt < 4; nt++)
          acc[mt][nt] = __builtin_amdgcn_mfma_f32_16x16x32_bf16(
              af[mt], bfr[nt], acc[mt][nt], 0, 0, 0);
    }
  }

  // alpha = sum(qv)/sum(qc) from 288 partials (L2-hot; block-redundant)
  double av = qv[tid];
  double ac = (double)qc[tid];
  if (tid < 32) { av += qv[256 + tid]; ac += (double)qc[256 + tid]; }
#pragma unroll
  for (int off = 32; off; off >>= 1) {
    av += __shfl_down(av, off);
    ac += __shfl_down(ac, off);
  }
  if ((tid & 63) == 0) { ads[tid >> 6] = av; acs[tid >> 6] = ac; }
  __syncthreads();
  float alpha = (float)((ads[0] + ads[1] + ads[2] + ads[3]) /
                        (acs[0] + acs[1] + acs[2] + acs[3]));

  // epilogue: alpha * acc + bias, fp32 store
  // C/D layout (m89/m91): col = lane&15, row = (lane>>4)*4 + reg
#pragma unroll
  for (int mt = 0; mt < 4; mt++) {
    uint mb = bm * 128 + wm * 64 + mt * 16 + fq * 4;
#pragma unroll
    for (int r = 0; r < 4; r++) {
      float* orow = out + (size_t)(mb + r) * 256;
#pragma unroll
      for (int nt = 0; nt < 4; nt++) {
        uint n = bn * 128 + wn * 64 + nt * 16 + fr;
        orow[n] = acc[mt][nt][r] * alpha + bias[n];
      }
    }
  }
}

extern "C" void kernel_launch(void* const* d_in, const int* in_sizes, int n_in,
                              void* d_out, int out_size, void* d_ws, size_t ws_size,
                              hipStream_t stream) {
  const float* x = (const float*)d_in[0];
  const float* W = (const float*)d_in[1];
  const float* b = (const float*)d_in[2];
  float* out = (float*)d_out;

  double* pr = (double*)((char*)d_ws + PR_OFF);
  double* qv = (double*)((char*)d_ws + QV_OFF);
  unsigned long long* qc = (unsigned long long*)((char*)d_ws + QC_OFF);
  ushort* WqT = (ushort*)((char*)d_ws + WQT_OFF);

  sumabs_kernel<<<RED_BLOCKS, 256, 0, stream>>>(W, pr);
  quant_kernel<<<RED_BLOCKS, 256, 0, stream>>>(W, WqT, pr, qv, qc);
  conv_kernel<<<1568, 256, 0, stream>>>(x, WqT, qv, qc, b, out);
}

// Round 6
// 292.594 us; speedup vs baseline: 1.1760x; 1.1760x over previous
//
#include <hip/hip_runtime.h>
#include <hip/hip_bf16.h>
#include <stdint.h>

// TernaryConv2d: y = conv2d(x, alpha*ternary(W), SAME) + b
// x: (32,56,56,256) NHWC fp32, W: (3,3,256,256) HWIO fp32, b: (256,) fp32
// Implicit GEMM: M=100352, N=256, K=2304. bf16 MFMA, alpha fp32 epilogue.
//
// R1: reduction atomics fixed (670->349).
// R2: XOR-swizzled LDS, kc-outer/tap-inner K-loop, fused sumabs (349->299).
// R3: 256x256/8-phase REGRESSED (grid-packing tail: 392 blocks). REVERTED.
// R4/R5: atomics/memset removed (294). ~110us fixed harness residue identified.
// R6/R7: pad fused into conv (fp32 A-staging, serial then pipelined): conv
//     223-225us BOTH WAYS, MfmaUtil pinned 22%. Diagnosis: per-K-step
//     cvt/pack/ds_write/predication VALU ~= MFMA cycles; with 2 waves/SIMD the
//     pipes split issue ~50/50. global_load_lds staging has zero per-step
//     VALU — that's R2's 42%. Fused path ABANDONED.
// R8: conv = R5 byte-identical (124us proven). Pad restructured: interior
//     (branch-free, perfectly linear reads) / border-zeros (912 blocks) /
//     sumabs all fused in one grid. Pad ideal 25us, was ~50.
//
// ws layout:
//   [0..2303]           : pr[288] double  — per-block sum|W| partials
//   [2560..4863]        : qv[288] double  — per-block sum|W beyond t| partials
//   [5120..7423]        : qc[288] ull     — per-block count-beyond partials
//   [8192..1187839]     : WqT bf16 [256 co][2304 k]  (k = tap*256 + ci)
//   [1187840..56303615] : xpad bf16 [32][58][58][256] (zero-padded halo)

typedef __attribute__((ext_vector_type(8))) short short8;
typedef __attribute__((ext_vector_type(4))) float floatx4;

#define NW_ELEMS 589824        // 3*3*256*256
#define K_TOTAL 2304
#define PR_OFF 0
#define QV_OFF 2560
#define QC_OFF 5120
#define WQT_OFF 8192
#define XPAD_OFF 1187840
#define RED_BLOCKS 288         // 288*256*8 == NW_ELEMS exactly
#define BORDER_BLOCKS 912      // 32*228 border px * 32 ch-chunks / 256 thr
#define INT_BLOCKS 12544       // 32*56*56*256 / 8 / 256

__device__ __forceinline__ void async16(const void* g, void* l) {
  __builtin_amdgcn_global_load_lds(
      (const __attribute__((address_space(1))) void*)g,
      (__attribute__((address_space(3))) void*)l, 16, 0, 0);
}

__device__ __forceinline__ ushort f2bf(float f) {
  __hip_bfloat16 h = __float2bfloat16(f);
  return *reinterpret_cast<ushort*>(&h);
}

// ---- fused pre-pass: [0,288) sum|W|; [288,1200) border zeros; rest interior.
__global__ __launch_bounds__(256) void pad_sumabs_kernel(
    const float* __restrict__ x, ushort* __restrict__ xpad,
    const float* __restrict__ W, double* __restrict__ pr) {
  if (blockIdx.x < RED_BLOCKS) {
    __shared__ double sds[4];
    double v = 0.0;
#pragma unroll
    for (int j = 0; j < 8; j++) {
      uint i = (blockIdx.x * 8 + j) * 256 + threadIdx.x;
      v += (double)fabsf(W[i]);
    }
#pragma unroll
    for (int off = 32; off; off >>= 1) v += __shfl_down(v, off);
    if ((threadIdx.x & 63) == 0) sds[threadIdx.x >> 6] = v;
    __syncthreads();
    if (threadIdx.x == 0) pr[blockIdx.x] = sds[0] + sds[1] + sds[2] + sds[3];
    return;
  }
  if (blockIdx.x < RED_BLOCKS + BORDER_BLOCKS) {
    // border pixels: per image 228 = top58 + bottom58 + left56 + right56
    uint idx = (blockIdx.x - RED_BLOCKS) * 256 + threadIdx.x;
    uint c8 = idx & 31;
    uint bp = idx >> 5;          // 0..7295
    uint n = bp / 228;
    uint pos = bp - n * 228;
    uint hh, ww;
    if (pos < 58) { hh = 0; ww = pos; }
    else if (pos < 116) { hh = 57; ww = pos - 58; }
    else if (pos < 172) { hh = pos - 115; ww = 0; }
    else { hh = pos - 171; ww = 57; }
    uint sp = n * 3364 + hh * 58 + ww;
    uint4 z = {0, 0, 0, 0};
    *(uint4*)(xpad + ((size_t)sp * 256 + c8 * 8)) = z;
    return;
  }
  // interior: branch-free, reads are perfectly linear in idx
  uint idx = (blockIdx.x - RED_BLOCKS - BORDER_BLOCKS) * 256 + threadIdx.x;
  uint c8 = idx & 31;
  uint sp = idx >> 5;            // n*3136 + hh*56 + ww  (unpadded index)
  uint ww = sp % 56;
  uint t = sp / 56;
  uint hh = t % 56;
  uint n = t / 56;
  const float* src = x + (size_t)idx * 8;   // == sp*256 + c8*8, linear
  float4 f0 = *(const float4*)src;
  float4 f1 = *(const float4*)(src + 4);
  ushort u[8];
  u[0] = f2bf(f0.x); u[1] = f2bf(f0.y); u[2] = f2bf(f0.z); u[3] = f2bf(f0.w);
  u[4] = f2bf(f1.x); u[5] = f2bf(f1.y); u[6] = f2bf(f1.z); u[7] = f2bf(f1.w);
  size_t dsp = (size_t)n * 3364 + (hh + 1) * 58 + (ww + 1);
  *(uint4*)(xpad + (dsp * 256 + c8 * 8)) = *(uint4*)u;
}

// ---- ternarize: WqT[co][k] in {-1,0,+1}; per-block alpha-stat partials ----
__global__ __launch_bounds__(256) void quant_kernel(
    const float* __restrict__ W, ushort* __restrict__ WqT,
    const double* __restrict__ pr, double* __restrict__ qv,
    unsigned long long* __restrict__ qc) {
  __shared__ double sds[4];
  __shared__ unsigned long long cds[4];
  double p = pr[threadIdx.x];
  if (threadIdx.x < 32) p += pr[256 + threadIdx.x];
#pragma unroll
  for (int off = 32; off; off >>= 1) p += __shfl_down(p, off);
  if ((threadIdx.x & 63) == 0) sds[threadIdx.x >> 6] = p;
  __syncthreads();
  double s = sds[0] + sds[1] + sds[2] + sds[3];
  float t = (float)(0.7 * (s / (double)NW_ELEMS));
  __syncthreads();  // sds reused below

  double v = 0.0;
  unsigned long long cnt = 0;
  ushort u[8];
#pragma unroll
  for (int j = 0; j < 8; j++) {
    uint i = (blockIdx.x * 8 + j) * 256 + threadIdx.x;
    float w = W[i];
    bool pos = (w > t), neg = (w < -t);
    u[j] = pos ? (ushort)0x3F80 : (neg ? (ushort)0xBF80 : (ushort)0);
    if (pos || neg) { v += (double)fabsf(w); cnt++; }
  }
  // thread (bid,tid) owns WqT[co=tid][k = bid*8 .. bid*8+7]: one 16B store
  *(uint4*)(WqT + (size_t)threadIdx.x * K_TOTAL + blockIdx.x * 8) = *(uint4*)u;
#pragma unroll
  for (int off = 32; off; off >>= 1) {
    v += __shfl_down(v, off);
    cnt += __shfl_down(cnt, off);
  }
  if ((threadIdx.x & 63) == 0) { sds[threadIdx.x >> 6] = v; cds[threadIdx.x >> 6] = cnt; }
  __syncthreads();
  if (threadIdx.x == 0) {
    qv[blockIdx.x] = sds[0] + sds[1] + sds[2] + sds[3];
    qc[blockIdx.x] = cds[0] + cds[1] + cds[2] + cds[3];
  }
}

// ---- implicit-GEMM conv: 128x128 tile, BK=64, 16x16x32 bf16 MFMA ----
// (R2/R5 structure, verified 124us / 42% MfmaUtil / 0 bank conflicts. UNTOUCHED.)
// LDS rows: 64 ushort = 128 B = 32 banks. Chunk c of row r stored at chunk
// slot c (staging loads global chunk c^(r&7)), readers fetch slot
// (kk*4+fq)^(fr&7): every bank gets exactly 8 dword accesses per b128 wave
// read -> conflict-free.
__global__ __launch_bounds__(256, 2) void conv_kernel(
    const ushort* __restrict__ xpad, const ushort* __restrict__ WqT,
    const double* __restrict__ qv, const unsigned long long* __restrict__ qc,
    const float* __restrict__ bias, float* __restrict__ out) {
  __shared__ __attribute__((aligned(16))) ushort Alds[128 * 64];  // 16 KB
  __shared__ __attribute__((aligned(16))) ushort Blds[128 * 64];  // 16 KB
  __shared__ double ads[4];
  __shared__ double acs[4];
  uint tid = threadIdx.x;
  uint bm = blockIdx.x >> 1, bn = blockIdx.x & 1;

  // staging: thread (rbase,chunk) loads global chunk ceff = chunk^(rbase&7)
  uint chunk = tid & 7;
  uint rbase = tid >> 3;       // 0..31
  uint ceff = chunk ^ (rbase & 7);
  const ushort* asrc[4];
  const ushort* bsrc[4];
#pragma unroll
  for (int i = 0; i < 4; i++) {
    uint row = i * 32 + rbase;
    uint gm = bm * 128 + row;
    uint n = gm / 3136;
    uint rem = gm - n * 3136;
    uint h = rem / 56;
    uint w = rem - h * 56;
    asrc[i] = xpad + (((size_t)(n * 58 + h) * 58 + w) * 256 + ceff * 8);
    bsrc[i] = WqT + ((size_t)(bn * 128 + row) * K_TOTAL + ceff * 8);
  }

  floatx4 acc[4][4];
#pragma unroll
  for (int mt = 0; mt < 4; mt++)
#pragma unroll
    for (int nt = 0; nt < 4; nt++) acc[mt][nt] = (floatx4){0.f, 0.f, 0.f, 0.f};

  uint lane = tid & 63;
  uint wv = tid >> 6;
  uint wm = wv >> 1, wn = wv & 1;   // 2x2 wave grid, each 64x64
  uint fr = lane & 15, fq = lane >> 4;
  uint a_row = (wm * 64 + fr) * 128;  // + mt*2048 + swz-chunk*16 (bytes)
  uint b_row = (wn * 64 + fr) * 128;
  uint swz = (fr & 7) * 16;           // XOR byte offset applied to chunk slot

  // K-loop: kc-outer, tap-inner (taps 1 step apart -> A re-reads L2-hot)
  for (int ks = 0; ks < 36; ks++) {
    uint kcq = (uint)ks / 9;
    uint tap = (uint)ks - kcq * 9;
    uint ky = tap / 3;
    uint kx = tap - ky * 3;
    uint aoffe = (ky * 58 + kx) * 256 + kcq * 64;  // elements into xpad
    uint boffe = tap * 256 + kcq * 64;             // elements along WqT row

    __syncthreads();  // previous tile fully consumed
#pragma unroll
    for (int i = 0; i < 4; i++)
      async16(asrc[i] + aoffe, (char*)Alds + i * 4096 + tid * 16);
#pragma unroll
    for (int i = 0; i < 4; i++)
      async16(bsrc[i] + boffe, (char*)Blds + i * 4096 + tid * 16);
    __syncthreads();  // drains vmcnt -> staging complete

#pragma unroll
    for (int kk = 0; kk < 2; kk++) {
      uint csl = ((uint)(kk * 64) + fq * 16) ^ swz;  // swizzled chunk slot
      short8 af[4], bfr[4];
#pragma unroll
      for (int mt = 0; mt < 4; mt++)
        af[mt] = *(const short8*)((const char*)Alds + a_row + mt * 2048 + csl);
#pragma unroll
      for (int nt = 0; nt < 4; nt++)
        bfr[nt] = *(const short8*)((const char*)Blds + b_row + nt * 2048 + csl);
#pragma unroll
      for (int mt = 0; mt < 4; mt++)
#pragma unroll
        for (int nt = 0; nt < 4; nt++)
          acc[mt][nt] = __builtin_amdgcn_mfma_f32_16x16x32_bf16(
              af[mt], bfr[nt], acc[mt][nt], 0, 0, 0);
    }
  }

  // alpha = sum(qv)/sum(qc) from 288 partials (L2-hot; block-redundant)
  double av = qv[tid];
  double ac = (double)qc[tid];
  if (tid < 32) { av += qv[256 + tid]; ac += (double)qc[256 + tid]; }
#pragma unroll
  for (int off = 32; off; off >>= 1) {
    av += __shfl_down(av, off);
    ac += __shfl_down(ac, off);
  }
  if ((tid & 63) == 0) { ads[tid >> 6] = av; acs[tid >> 6] = ac; }
  __syncthreads();
  float alpha = (float)((ads[0] + ads[1] + ads[2] + ads[3]) /
                        (acs[0] + acs[1] + acs[2] + acs[3]));

  // epilogue: alpha * acc + bias, fp32 store
  // C/D layout (m89/m91): col = lane&15, row = (lane>>4)*4 + reg
#pragma unroll
  for (int mt = 0; mt < 4; mt++) {
    uint mb = bm * 128 + wm * 64 + mt * 16 + fq * 4;
#pragma unroll
    for (int r = 0; r < 4; r++) {
      float* orow = out + (size_t)(mb + r) * 256;
#pragma unroll
      for (int nt = 0; nt < 4; nt++) {
        uint n = bn * 128 + wn * 64 + nt * 16 + fr;
        orow[n] = acc[mt][nt][r] * alpha + bias[n];
      }
    }
  }
}

extern "C" void kernel_launch(void* const* d_in, const int* in_sizes, int n_in,
                              void* d_out, int out_size, void* d_ws, size_t ws_size,
                              hipStream_t stream) {
  const float* x = (const float*)d_in[0];
  const float* W = (const float*)d_in[1];
  const float* b = (const float*)d_in[2];
  float* out = (float*)d_out;

  double* pr = (double*)((char*)d_ws + PR_OFF);
  double* qv = (double*)((char*)d_ws + QV_OFF);
  unsigned long long* qc = (unsigned long long*)((char*)d_ws + QC_OFF);
  ushort* WqT = (ushort*)((char*)d_ws + WQT_OFF);
  ushort* xpad = (ushort*)((char*)d_ws + XPAD_OFF);

  pad_sumabs_kernel<<<RED_BLOCKS + BORDER_BLOCKS + INT_BLOCKS, 256, 0, stream>>>(
      x, xpad, W, pr);
  quant_kernel<<<RED_BLOCKS, 256, 0, stream>>>(W, WqT, pr, qv, qc);
  conv_kernel<<<1568, 256, 0, stream>>>(xpad, WqT, qv, qc, b, out);
}

// Round 8
// 291.958 us; speedup vs baseline: 1.1786x; 1.0022x over previous
//
#include <hip/hip_runtime.h>
#include <hip/hip_bf16.h>
#include <stdint.h>

// TernaryConv2d: y = conv2d(x, alpha*ternary(W), SAME) + b
// x: (32,56,56,256) NHWC fp32, W: (3,3,256,256) HWIO fp32, b: (256,) fp32
// Implicit GEMM: M=100352, N=256, K=2304. bf16 MFMA, alpha fp32 epilogue.
//
// R1: reduction atomics fixed (670->349).
// R2: XOR-swizzled LDS, kc-outer/tap-inner K-loop, fused sumabs (349->299).
// R3: 256x256/8-phase REGRESSED (grid-packing tail: 392 blocks). REVERTED.
// R4/R5: atomics/memset removed (294). ~110us fixed harness residue identified.
// R6/R7: pad fused into conv: conv 223-225 BOTH serial and pipelined; staging
//     VALU ~= MFMA cycles -> pipes split issue 50/50. ABANDONED.
// R8: branch-free interior/border pad: total 292.6 (wash) => pad is already
//     near its BW roofline; earlier "pad=50us" conflated ws-poison cost.
// R9: XCD-chunked block swizzle on conv (T1). FETCH=110MB = 2x xpad footprint
//     because the (bm,0)/(bm,1) pair (identical A-panel) round-robins to
//     DIFFERENT XCD L2s. sbid=(bid&7)*196+(bid>>3) gives each XCD contiguous
//     bm-tiles, pairs together; per-XCD working set ~3.9MB fits 4MB L2.
//     Shorter L2-hit drain before each barrier -> higher MfmaUtil.
// R10: resubmit of R9 — infra error ("container failed twice"), never
//     reached the GPU. sbid remap re-audited: bijective on [0,1568).
//
// ws layout:
//   [0..2303]           : pr[288] double  — per-block sum|W| partials
//   [2560..4863]        : qv[288] double  — per-block sum|W beyond t| partials
//   [5120..7423]        : qc[288] ull     — per-block count-beyond partials
//   [8192..1187839]     : WqT bf16 [256 co][2304 k]  (k = tap*256 + ci)
//   [1187840..56303615] : xpad bf16 [32][58][58][256] (zero-padded halo)

typedef __attribute__((ext_vector_type(8))) short short8;
typedef __attribute__((ext_vector_type(4))) float floatx4;

#define NW_ELEMS 589824        // 3*3*256*256
#define K_TOTAL 2304
#define PR_OFF 0
#define QV_OFF 2560
#define QC_OFF 5120
#define WQT_OFF 8192
#define XPAD_OFF 1187840
#define RED_BLOCKS 288         // 288*256*8 == NW_ELEMS exactly
#define BORDER_BLOCKS 912      // 32*228 border px * 32 ch-chunks / 256 thr
#define INT_BLOCKS 12544       // 32*56*56*256 / 8 / 256

__device__ __forceinline__ void async16(const void* g, void* l) {
  __builtin_amdgcn_global_load_lds(
      (const __attribute__((address_space(1))) void*)g,
      (__attribute__((address_space(3))) void*)l, 16, 0, 0);
}

__device__ __forceinline__ ushort f2bf(float f) {
  __hip_bfloat16 h = __float2bfloat16(f);
  return *reinterpret_cast<ushort*>(&h);
}

// ---- fused pre-pass: [0,288) sum|W|; [288,1200) border zeros; rest interior.
__global__ __launch_bounds__(256) void pad_sumabs_kernel(
    const float* __restrict__ x, ushort* __restrict__ xpad,
    const float* __restrict__ W, double* __restrict__ pr) {
  if (blockIdx.x < RED_BLOCKS) {
    __shared__ double sds[4];
    double v = 0.0;
#pragma unroll
    for (int j = 0; j < 8; j++) {
      uint i = (blockIdx.x * 8 + j) * 256 + threadIdx.x;
      v += (double)fabsf(W[i]);
    }
#pragma unroll
    for (int off = 32; off; off >>= 1) v += __shfl_down(v, off);
    if ((threadIdx.x & 63) == 0) sds[threadIdx.x >> 6] = v;
    __syncthreads();
    if (threadIdx.x == 0) pr[blockIdx.x] = sds[0] + sds[1] + sds[2] + sds[3];
    return;
  }
  if (blockIdx.x < RED_BLOCKS + BORDER_BLOCKS) {
    // border pixels: per image 228 = top58 + bottom58 + left56 + right56
    uint idx = (blockIdx.x - RED_BLOCKS) * 256 + threadIdx.x;
    uint c8 = idx & 31;
    uint bp = idx >> 5;          // 0..7295
    uint n = bp / 228;
    uint pos = bp - n * 228;
    uint hh, ww;
    if (pos < 58) { hh = 0; ww = pos; }
    else if (pos < 116) { hh = 57; ww = pos - 58; }
    else if (pos < 172) { hh = pos - 115; ww = 0; }
    else { hh = pos - 171; ww = 57; }
    uint sp = n * 3364 + hh * 58 + ww;
    uint4 z = {0, 0, 0, 0};
    *(uint4*)(xpad + ((size_t)sp * 256 + c8 * 8)) = z;
    return;
  }
  // interior: branch-free, reads are perfectly linear in idx
  uint idx = (blockIdx.x - RED_BLOCKS - BORDER_BLOCKS) * 256 + threadIdx.x;
  uint c8 = idx & 31;
  uint sp = idx >> 5;            // n*3136 + hh*56 + ww  (unpadded index)
  uint ww = sp % 56;
  uint t = sp / 56;
  uint hh = t % 56;
  uint n = t / 56;
  const float* src = x + (size_t)idx * 8;   // == sp*256 + c8*8, linear
  float4 f0 = *(const float4*)src;
  float4 f1 = *(const float4*)(src + 4);
  ushort u[8];
  u[0] = f2bf(f0.x); u[1] = f2bf(f0.y); u[2] = f2bf(f0.z); u[3] = f2bf(f0.w);
  u[4] = f2bf(f1.x); u[5] = f2bf(f1.y); u[6] = f2bf(f1.z); u[7] = f2bf(f1.w);
  size_t dsp = (size_t)n * 3364 + (hh + 1) * 58 + (ww + 1);
  *(uint4*)(xpad + (dsp * 256 + c8 * 8)) = *(uint4*)u;
}

// ---- ternarize: WqT[co][k] in {-1,0,+1}; per-block alpha-stat partials ----
__global__ __launch_bounds__(256) void quant_kernel(
    const float* __restrict__ W, ushort* __restrict__ WqT,
    const double* __restrict__ pr, double* __restrict__ qv,
    unsigned long long* __restrict__ qc) {
  __shared__ double sds[4];
  __shared__ unsigned long long cds[4];
  double p = pr[threadIdx.x];
  if (threadIdx.x < 32) p += pr[256 + threadIdx.x];
#pragma unroll
  for (int off = 32; off; off >>= 1) p += __shfl_down(p, off);
  if ((threadIdx.x & 63) == 0) sds[threadIdx.x >> 6] = p;
  __syncthreads();
  double s = sds[0] + sds[1] + sds[2] + sds[3];
  float t = (float)(0.7 * (s / (double)NW_ELEMS));
  __syncthreads();  // sds reused below

  double v = 0.0;
  unsigned long long cnt = 0;
  ushort u[8];
#pragma unroll
  for (int j = 0; j < 8; j++) {
    uint i = (blockIdx.x * 8 + j) * 256 + threadIdx.x;
    float w = W[i];
    bool pos = (w > t), neg = (w < -t);
    u[j] = pos ? (ushort)0x3F80 : (neg ? (ushort)0xBF80 : (ushort)0);
    if (pos || neg) { v += (double)fabsf(w); cnt++; }
  }
  // thread (bid,tid) owns WqT[co=tid][k = bid*8 .. bid*8+7]: one 16B store
  *(uint4*)(WqT + (size_t)threadIdx.x * K_TOTAL + blockIdx.x * 8) = *(uint4*)u;
#pragma unroll
  for (int off = 32; off; off >>= 1) {
    v += __shfl_down(v, off);
    cnt += __shfl_down(cnt, off);
  }
  if ((threadIdx.x & 63) == 0) { sds[threadIdx.x >> 6] = v; cds[threadIdx.x >> 6] = cnt; }
  __syncthreads();
  if (threadIdx.x == 0) {
    qv[blockIdx.x] = sds[0] + sds[1] + sds[2] + sds[3];
    qc[blockIdx.x] = cds[0] + cds[1] + cds[2] + cds[3];
  }
}

// ---- implicit-GEMM conv: 128x128 tile, BK=64, 16x16x32 bf16 MFMA ----
// (R2/R5 compute structure, verified 124-125us / 42% MfmaUtil / 0 conflicts.)
// R9: XCD-chunked swizzle. HW round-robins consecutive blockIdx across the
// 8 XCDs; sbid=(bid&7)*196+(bid>>3) (bijective, 1568=8*196) hands each XCD
// a contiguous sbid range -> contiguous bm tiles with both bn halves (which
// share the A-panel) on the SAME XCD L2. Only the bm/bn derivation changes.
__global__ __launch_bounds__(256, 2) void conv_kernel(
    const ushort* __restrict__ xpad, const ushort* __restrict__ WqT,
    const double* __restrict__ qv, const unsigned long long* __restrict__ qc,
    const float* __restrict__ bias, float* __restrict__ out) {
  __shared__ __attribute__((aligned(16))) ushort Alds[128 * 64];  // 16 KB
  __shared__ __attribute__((aligned(16))) ushort Blds[128 * 64];  // 16 KB
  __shared__ double ads[4];
  __shared__ double acs[4];
  uint tid = threadIdx.x;
  uint bid = blockIdx.x;
  uint sbid = (bid & 7) * 196 + (bid >> 3);   // XCD-chunked remap
  uint bm = sbid >> 1, bn = sbid & 1;

  // staging: thread (rbase,chunk) loads global chunk ceff = chunk^(rbase&7)
  uint chunk = tid & 7;
  uint rbase = tid >> 3;       // 0..31
  uint ceff = chunk ^ (rbase & 7);
  const ushort* asrc[4];
  const ushort* bsrc[4];
#pragma unroll
  for (int i = 0; i < 4; i++) {
    uint row = i * 32 + rbase;
    uint gm = bm * 128 + row;
    uint n = gm / 3136;
    uint rem = gm - n * 3136;
    uint h = rem / 56;
    uint w = rem - h * 56;
    asrc[i] = xpad + (((size_t)(n * 58 + h) * 58 + w) * 256 + ceff * 8);
    bsrc[i] = WqT + ((size_t)(bn * 128 + row) * K_TOTAL + ceff * 8);
  }

  floatx4 acc[4][4];
#pragma unroll
  for (int mt = 0; mt < 4; mt++)
#pragma unroll
    for (int nt = 0; nt < 4; nt++) acc[mt][nt] = (floatx4){0.f, 0.f, 0.f, 0.f};

  uint lane = tid & 63;
  uint wv = tid >> 6;
  uint wm = wv >> 1, wn = wv & 1;   // 2x2 wave grid, each 64x64
  uint fr = lane & 15, fq = lane >> 4;
  uint a_row = (wm * 64 + fr) * 128;  // + mt*2048 + swz-chunk*16 (bytes)
  uint b_row = (wn * 64 + fr) * 128;
  uint swz = (fr & 7) * 16;           // XOR byte offset applied to chunk slot

  // K-loop: kc-outer, tap-inner (taps 1 step apart -> A re-reads L2-hot)
  for (int ks = 0; ks < 36; ks++) {
    uint kcq = (uint)ks / 9;
    uint tap = (uint)ks - kcq * 9;
    uint ky = tap / 3;
    uint kx = tap - ky * 3;
    uint aoffe = (ky * 58 + kx) * 256 + kcq * 64;  // elements into xpad
    uint boffe = tap * 256 + kcq * 64;             // elements along WqT row

    __syncthreads();  // previous tile fully consumed
#pragma unroll
    for (int i = 0; i < 4; i++)
      async16(asrc[i] + aoffe, (char*)Alds + i * 4096 + tid * 16);
#pragma unroll
    for (int i = 0; i < 4; i++)
      async16(bsrc[i] + boffe, (char*)Blds + i * 4096 + tid * 16);
    __syncthreads();  // drains vmcnt -> staging complete

#pragma unroll
    for (int kk = 0; kk < 2; kk++) {
      uint csl = ((uint)(kk * 64) + fq * 16) ^ swz;  // swizzled chunk slot
      short8 af[4], bfr[4];
#pragma unroll
      for (int mt = 0; mt < 4; mt++)
        af[mt] = *(const short8*)((const char*)Alds + a_row + mt * 2048 + csl);
#pragma unroll
      for (int nt = 0; nt < 4; nt++)
        bfr[nt] = *(const short8*)((const char*)Blds + b_row + nt * 2048 + csl);
#pragma unroll
      for (int mt = 0; mt < 4; mt++)
#pragma unroll
        for (int nt = 0; nt < 4; nt++)
          acc[mt][nt] = __builtin_amdgcn_mfma_f32_16x16x32_bf16(
              af[mt], bfr[nt], acc[mt][nt], 0, 0, 0);
    }
  }

  // alpha = sum(qv)/sum(qc) from 288 partials (L2-hot; block-redundant)
  double av = qv[tid];
  double ac = (double)qc[tid];
  if (tid < 32) { av += qv[256 + tid]; ac += (double)qc[256 + tid]; }
#pragma unroll
  for (int off = 32; off; off >>= 1) {
    av += __shfl_down(av, off);
    ac += __shfl_down(ac, off);
  }
  if ((tid & 63) == 0) { ads[tid >> 6] = av; acs[tid >> 6] = ac; }
  __syncthreads();
  float alpha = (float)((ads[0] + ads[1] + ads[2] + ads[3]) /
                        (acs[0] + acs[1] + acs[2] + acs[3]));

  // epilogue: alpha * acc + bias, fp32 store
  // C/D layout (m89/m91): col = lane&15, row = (lane>>4)*4 + reg
#pragma unroll
  for (int mt = 0; mt < 4; mt++) {
    uint mb = bm * 128 + wm * 64 + mt * 16 + fq * 4;
#pragma unroll
    for (int r = 0; r < 4; r++) {
      float* orow = out + (size_t)(mb + r) * 256;
#pragma unroll
      for (int nt = 0; nt < 4; nt++) {
        uint n = bn * 128 + wn * 64 + nt * 16 + fr;
        orow[n] = acc[mt][nt][r] * alpha + bias[n];
      }
    }
  }
}

extern "C" void kernel_launch(void* const* d_in, const int* in_sizes, int n_in,
                              void* d_out, int out_size, void* d_ws, size_t ws_size,
                              hipStream_t stream) {
  const float* x = (const float*)d_in[0];
  const float* W = (const float*)d_in[1];
  const float* b = (const float*)d_in[2];
  float* out = (float*)d_out;

  double* pr = (double*)((char*)d_ws + PR_OFF);
  double* qv = (double*)((char*)d_ws + QV_OFF);
  unsigned long long* qc = (unsigned long long*)((char*)d_ws + QC_OFF);
  ushort* WqT = (ushort*)((char*)d_ws + WQT_OFF);
  ushort* xpad = (ushort*)((char*)d_ws + XPAD_OFF);

  pad_sumabs_kernel<<<RED_BLOCKS + BORDER_BLOCKS + INT_BLOCKS, 256, 0, stream>>>(
      x, xpad, W, pr);
  quant_kernel<<<RED_BLOCKS, 256, 0, stream>>>(W, WqT, pr, qv, qc);
  conv_kernel<<<1568, 256, 0, stream>>>(xpad, WqT, qv, qc, b, out);
}